// Round 1
// baseline (164.679 us; speedup 1.0000x reference)
//
#include <hip/hip_runtime.h>

typedef __bf16 bf16x8 __attribute__((ext_vector_type(8)));
typedef __bf16 bf16x4 __attribute__((ext_vector_type(4)));
typedef float  f32x4  __attribute__((ext_vector_type(4)));

#define NGRAPH 256
#define HDIM   256
#define DDIM   128
#define ODIM   128

// ---------------------------------------------------------------------------
// prep: swizzle W_enc (fp32 [128][256] row-major) into MFMA B-fragment order,
// bf16. Layout: Bsw[((kk*16+nt)*64+lane)*8 + j] = W_enc[kk*32+quad*8+j][nt*16+m]
// so each lane's 8 B-operand values are one contiguous 16-byte load.
// ---------------------------------------------------------------------------
__global__ __launch_bounds__(256) void prep_kernel(const float* __restrict__ W_enc,
                                                   __bf16* __restrict__ Bsw) {
  int tid  = blockIdx.x * 256 + threadIdx.x;   // [0, 4096)
  int lane = tid & 63;
  int t2   = tid >> 6;                          // [0, 64)
  int nt   = t2 & 15;
  int kk   = t2 >> 4;                           // [0, 4)
  int quad = lane >> 4, m = lane & 15;
  int col  = nt * 16 + m;
  bf16x8 frag;
#pragma unroll
  for (int j = 0; j < 8; ++j) {
    int k   = kk * 32 + quad * 8 + j;
    frag[j] = (__bf16)W_enc[k * HDIM + col];
  }
  *(bf16x8*)(Bsw + (size_t)tid * 8) = frag;
}

// ---------------------------------------------------------------------------
// Fused encoder + segment-sum.
// Block = 256 threads (4 waves), handles 64 consecutive nodes x all 256 cols.
// Wave w owns columns [w*64, w*64+64) as 4 MFMA n-tiles; each wave covers all
// 64 rows (4 m-tiles). seg[g][col] += relu(x@W_enc + b)[row][col] summed over
// rows of graph g. batch is sorted -> 64-row block is usually one graph.
// ---------------------------------------------------------------------------
__global__ __launch_bounds__(256) void enc_kernel(const float* __restrict__ x,
                                                  const int* __restrict__ batch,
                                                  const __bf16* __restrict__ Bsw,
                                                  const float* __restrict__ b_enc,
                                                  float* __restrict__ seg) {
  __shared__ __align__(16) __bf16 Albuf[64 * 136];  // row stride 136 (pad 8)
  __shared__ int gbuf[64];
  const int  t    = threadIdx.x;
  const long base = (long)blockIdx.x * 64;

  // stage 64x128 fp32 -> bf16 into LDS
  const float4* xsrc = (const float4*)(x + base * DDIM);
#pragma unroll
  for (int p = 0; p < 8; ++p) {
    int    i   = t + p * 256;          // float4 index; 32 per row
    float4 v   = xsrc[i];
    int    row = i >> 5, c4 = i & 31;
    bf16x4 bv;
    bv[0] = (__bf16)v.x; bv[1] = (__bf16)v.y;
    bv[2] = (__bf16)v.z; bv[3] = (__bf16)v.w;
    *(bf16x4*)&Albuf[row * 136 + c4 * 4] = bv;
  }
  if (t < 64) gbuf[t] = batch[base + t];
  __syncthreads();

  const int lane = t & 63, wave = t >> 6;
  const int m = lane & 15, quad = lane >> 4;

  f32x4 acc[4][4];   // [n-tile][m-tile]
#pragma unroll
  for (int a = 0; a < 4; ++a)
#pragma unroll
    for (int b = 0; b < 4; ++b) acc[a][b] = (f32x4){0.f, 0.f, 0.f, 0.f};

#pragma unroll
  for (int kk = 0; kk < 4; ++kk) {
    bf16x8 afr[4];
#pragma unroll
    for (int mt = 0; mt < 4; ++mt)
      afr[mt] = *(const bf16x8*)&Albuf[(mt * 16 + m) * 136 + kk * 32 + quad * 8];
    bf16x8 bfr[4];
#pragma unroll
    for (int ntl = 0; ntl < 4; ++ntl) {
      int ntg  = wave * 4 + ntl;
      bfr[ntl] = *(const bf16x8*)(Bsw + (size_t)(((kk * 16 + ntg) * 64) + lane) * 8);
    }
#pragma unroll
    for (int ntl = 0; ntl < 4; ++ntl)
#pragma unroll
      for (int mt = 0; mt < 4; ++mt)
        acc[ntl][mt] = __builtin_amdgcn_mfma_f32_16x16x32_bf16(
            afr[mt], bfr[ntl], acc[ntl][mt], 0, 0, 0);
  }

  // epilogue: relu + bias, then segment-reduce the 64 rows
  const bool uni = (gbuf[0] == gbuf[63]);   // sorted batch -> all 64 rows same g
#pragma unroll
  for (int ntl = 0; ntl < 4; ++ntl) {
    const int   col  = (wave * 4 + ntl) * 16 + m;
    const float bias = b_enc[col];
    if (uni) {
      float s = 0.f;
#pragma unroll
      for (int mt = 0; mt < 4; ++mt)
#pragma unroll
        for (int r = 0; r < 4; ++r)
          s += fmaxf(acc[ntl][mt][r] + bias, 0.f);
      s += __shfl_xor(s, 16, 64);
      s += __shfl_xor(s, 32, 64);
      if (quad == 0) atomicAdd(&seg[gbuf[0] * HDIM + col], s);
    } else {
      // rows for this lane, in increasing order: row = mt*16 + quad*4 + r
      int   grun = gbuf[quad * 4];
      float s    = 0.f;
#pragma unroll
      for (int mt = 0; mt < 4; ++mt)
#pragma unroll
        for (int r = 0; r < 4; ++r) {
          int   g = gbuf[mt * 16 + quad * 4 + r];
          float v = fmaxf(acc[ntl][mt][r] + bias, 0.f);
          if (g != grun) {
            atomicAdd(&seg[grun * HDIM + col], s);
            grun = g; s = v;
          } else {
            s += v;
          }
        }
      atomicAdd(&seg[grun * HDIM + col], s);
    }
  }
}

// ---------------------------------------------------------------------------
// Tail MLP chain, all row-wise: per graph g,
//   t1 = relu(seg[g]/8 @ Wv1 + bv1); t2 = t1 @ Wv2 + bv2  (== gf, V-mean is id)
//   p1 = relu(t2 @ Wp1 + bp1);       out = p1 @ Wp2 + bp2
// 2 graphs per block; thread j owns output column j of each layer.
// ---------------------------------------------------------------------------
#define RPB 2
__global__ __launch_bounds__(256) void mlp_kernel(
    const float* __restrict__ seg,
    const float* __restrict__ Wv1, const float* __restrict__ bv1,
    const float* __restrict__ Wv2, const float* __restrict__ bv2,
    const float* __restrict__ Wp1, const float* __restrict__ bp1,
    const float* __restrict__ Wp2, const float* __restrict__ bp2,
    float* __restrict__ out) {
  __shared__ float A[RPB][HDIM];
  __shared__ float B[RPB][HDIM];
  const int j  = threadIdx.x;
  const int g0 = blockIdx.x * RPB;

#pragma unroll
  for (int r = 0; r < RPB; ++r) A[r][j] = seg[(g0 + r) * HDIM + j] * 0.125f;
  __syncthreads();

  {  // layer 1: B = relu(A @ Wv1 + bv1)
    float acc[RPB] = {0.f, 0.f};
    for (int k = 0; k < HDIM; ++k) {
      float w = Wv1[k * HDIM + j];
#pragma unroll
      for (int r = 0; r < RPB; ++r) acc[r] += A[r][k] * w;
    }
#pragma unroll
    for (int r = 0; r < RPB; ++r) B[r][j] = fmaxf(acc[r] + bv1[j], 0.f);
  }
  __syncthreads();

  {  // layer 2: A = B @ Wv2 + bv2   (no relu)
    float acc[RPB] = {0.f, 0.f};
    for (int k = 0; k < HDIM; ++k) {
      float w = Wv2[k * HDIM + j];
#pragma unroll
      for (int r = 0; r < RPB; ++r) acc[r] += B[r][k] * w;
    }
    __syncthreads();
#pragma unroll
    for (int r = 0; r < RPB; ++r) A[r][j] = acc[r] + bv2[j];
  }
  __syncthreads();

  {  // layer 3: B = relu(A @ Wp1 + bp1)
    float acc[RPB] = {0.f, 0.f};
    for (int k = 0; k < HDIM; ++k) {
      float w = Wp1[k * HDIM + j];
#pragma unroll
      for (int r = 0; r < RPB; ++r) acc[r] += A[r][k] * w;
    }
#pragma unroll
    for (int r = 0; r < RPB; ++r) B[r][j] = fmaxf(acc[r] + bp1[j], 0.f);
  }
  __syncthreads();

  if (j < ODIM) {  // layer 4: out = B @ Wp2 + bp2
    float acc[RPB] = {0.f, 0.f};
    for (int k = 0; k < HDIM; ++k) {
      float w = Wp2[k * ODIM + j];
#pragma unroll
      for (int r = 0; r < RPB; ++r) acc[r] += B[r][k] * w;
    }
#pragma unroll
    for (int r = 0; r < RPB; ++r) out[(g0 + r) * ODIM + j] = acc[r] + bp2[j];
  }
}

// ---------------------------------------------------------------------------
extern "C" void kernel_launch(void* const* d_in, const int* in_sizes, int n_in,
                              void* d_out, int out_size, void* d_ws, size_t ws_size,
                              hipStream_t stream) {
  const float* x     = (const float*)d_in[0];
  // d_in[1] = edge_index : unused by the reference
  const int*   batch = (const int*)d_in[2];
  const float* W_enc = (const float*)d_in[3];
  const float* b_enc = (const float*)d_in[4];
  const float* W_v1  = (const float*)d_in[5];
  const float* b_v1  = (const float*)d_in[6];
  const float* W_v2  = (const float*)d_in[7];
  const float* b_v2  = (const float*)d_in[8];
  const float* W_p1  = (const float*)d_in[9];
  const float* b_p1  = (const float*)d_in[10];
  const float* W_p2  = (const float*)d_in[11];
  const float* b_p2  = (const float*)d_in[12];
  float* out = (float*)d_out;

  float*  seg = (float*)d_ws;                        // 256*256*4 = 262144 B
  __bf16* Bsw = (__bf16*)((char*)d_ws + 262144);     // 128*256*2 =  65536 B

  hipMemsetAsync(seg, 0, NGRAPH * HDIM * sizeof(float), stream);
  prep_kernel<<<16, 256, 0, stream>>>(W_enc, Bsw);
  enc_kernel<<<102400 / 64, 256, 0, stream>>>(x, batch, Bsw, b_enc, seg);
  mlp_kernel<<<NGRAPH / RPB, 256, 0, stream>>>(seg, W_v1, b_v1, W_v2, b_v2,
                                               W_p1, b_p1, W_p2, b_p2, out);
}

// Round 2
// 137.426 us; speedup vs baseline: 1.1983x; 1.1983x over previous
//
#include <hip/hip_runtime.h>

typedef __bf16 bf16x8 __attribute__((ext_vector_type(8)));
typedef __bf16 bf16x4 __attribute__((ext_vector_type(4)));
typedef float  f32x4  __attribute__((ext_vector_type(4)));

#define NGRAPH 256
#define HDIM   256
#define DDIM   128
#define ODIM   128

// ---------------------------------------------------------------------------
// prep: swizzle W_enc (fp32 [128][256] row-major) into MFMA B-fragment order,
// bf16. Layout: Bsw[((kk*16+nt)*64+lane)*8 + j] = W_enc[kk*32+quad*8+j][nt*16+m]
// so each lane's 8 B-operand values are one contiguous 16-byte load.
// ---------------------------------------------------------------------------
__global__ __launch_bounds__(256) void prep_kernel(const float* __restrict__ W_enc,
                                                   __bf16* __restrict__ Bsw) {
  int tid  = blockIdx.x * 256 + threadIdx.x;   // [0, 4096)
  int lane = tid & 63;
  int t2   = tid >> 6;                          // [0, 64)
  int nt   = t2 & 15;
  int kk   = t2 >> 4;                           // [0, 4)
  int quad = lane >> 4, m = lane & 15;
  int col  = nt * 16 + m;
  bf16x8 frag;
#pragma unroll
  for (int j = 0; j < 8; ++j) {
    int k   = kk * 32 + quad * 8 + j;
    frag[j] = (__bf16)W_enc[k * HDIM + col];
  }
  *(bf16x8*)(Bsw + (size_t)tid * 8) = frag;
}

// ---------------------------------------------------------------------------
// Fused encoder + segment-sum (unchanged from R1).
// ---------------------------------------------------------------------------
__global__ __launch_bounds__(256) void enc_kernel(const float* __restrict__ x,
                                                  const int* __restrict__ batch,
                                                  const __bf16* __restrict__ Bsw,
                                                  const float* __restrict__ b_enc,
                                                  float* __restrict__ seg) {
  __shared__ __align__(16) __bf16 Albuf[64 * 136];  // row stride 136 (pad 8)
  __shared__ int gbuf[64];
  const int  t    = threadIdx.x;
  const long base = (long)blockIdx.x * 64;

  // stage 64x128 fp32 -> bf16 into LDS
  const float4* xsrc = (const float4*)(x + base * DDIM);
#pragma unroll
  for (int p = 0; p < 8; ++p) {
    int    i   = t + p * 256;          // float4 index; 32 per row
    float4 v   = xsrc[i];
    int    row = i >> 5, c4 = i & 31;
    bf16x4 bv;
    bv[0] = (__bf16)v.x; bv[1] = (__bf16)v.y;
    bv[2] = (__bf16)v.z; bv[3] = (__bf16)v.w;
    *(bf16x4*)&Albuf[row * 136 + c4 * 4] = bv;
  }
  if (t < 64) gbuf[t] = batch[base + t];
  __syncthreads();

  const int lane = t & 63, wave = t >> 6;
  const int m = lane & 15, quad = lane >> 4;

  f32x4 acc[4][4];   // [n-tile][m-tile]
#pragma unroll
  for (int a = 0; a < 4; ++a)
#pragma unroll
    for (int b = 0; b < 4; ++b) acc[a][b] = (f32x4){0.f, 0.f, 0.f, 0.f};

#pragma unroll
  for (int kk = 0; kk < 4; ++kk) {
    bf16x8 afr[4];
#pragma unroll
    for (int mt = 0; mt < 4; ++mt)
      afr[mt] = *(const bf16x8*)&Albuf[(mt * 16 + m) * 136 + kk * 32 + quad * 8];
    bf16x8 bfr[4];
#pragma unroll
    for (int ntl = 0; ntl < 4; ++ntl) {
      int ntg  = wave * 4 + ntl;
      bfr[ntl] = *(const bf16x8*)(Bsw + (size_t)(((kk * 16 + ntg) * 64) + lane) * 8);
    }
#pragma unroll
    for (int ntl = 0; ntl < 4; ++ntl)
#pragma unroll
      for (int mt = 0; mt < 4; ++mt)
        acc[ntl][mt] = __builtin_amdgcn_mfma_f32_16x16x32_bf16(
            afr[mt], bfr[ntl], acc[ntl][mt], 0, 0, 0);
  }

  // epilogue: relu + bias, then segment-reduce the 64 rows
  const bool uni = (gbuf[0] == gbuf[63]);   // sorted batch -> all 64 rows same g
#pragma unroll
  for (int ntl = 0; ntl < 4; ++ntl) {
    const int   col  = (wave * 4 + ntl) * 16 + m;
    const float bias = b_enc[col];
    if (uni) {
      float s = 0.f;
#pragma unroll
      for (int mt = 0; mt < 4; ++mt)
#pragma unroll
        for (int r = 0; r < 4; ++r)
          s += fmaxf(acc[ntl][mt][r] + bias, 0.f);
      s += __shfl_xor(s, 16, 64);
      s += __shfl_xor(s, 32, 64);
      if (quad == 0) atomicAdd(&seg[gbuf[0] * HDIM + col], s);
    } else {
      // rows for this lane, in increasing order: row = mt*16 + quad*4 + r
      int   grun = gbuf[quad * 4];
      float s    = 0.f;
#pragma unroll
      for (int mt = 0; mt < 4; ++mt)
#pragma unroll
        for (int r = 0; r < 4; ++r) {
          int   g = gbuf[mt * 16 + quad * 4 + r];
          float v = fmaxf(acc[ntl][mt][r] + bias, 0.f);
          if (g != grun) {
            atomicAdd(&seg[grun * HDIM + col], s);
            grun = g; s = v;
          } else {
            s += v;
          }
        }
      atomicAdd(&seg[grun * HDIM + col], s);
    }
  }
}

// ---------------------------------------------------------------------------
// Tail MLP v2 — latency fix. One graph per block, grid=256 (all CUs busy).
// Per 256-wide layer: 256 threads = 4 k-chunks (one per wave) x 64 col-quads.
// Thread (rg, jq) accumulates cols [4jq,4jq+4) over k in [rg*64, rg*64+64)
// using float4 weight loads (16 B/lane, coalesced 1 KB/wave). Partials
// reduced through LDS. Input-vector reads are wave-uniform LDS broadcasts.
// Final layer (H->O=128): 8 k-chunks x 32 col-quads.
// ---------------------------------------------------------------------------
__device__ __forceinline__ void mlp_layer256(const float* __restrict__ buf_in,
                                             float* __restrict__ buf_out,
                                             float (*__restrict__ part)[HDIM],
                                             const float* __restrict__ W,
                                             const float* __restrict__ bias,
                                             bool relu, float scale, int t) {
  const int rg = t >> 6;          // wave id = k-chunk
  const int jq = t & 63;          // column quad
  f32x4 acc = {0.f, 0.f, 0.f, 0.f};
  const float4* wrow = (const float4*)(W + (size_t)rg * 64 * HDIM) + jq;
#pragma unroll 8
  for (int k = 0; k < 64; ++k) {
    float  a = buf_in[rg * 64 + k];        // wave-uniform broadcast
    float4 w = wrow[(size_t)k * (HDIM / 4)];
    acc[0] += a * w.x; acc[1] += a * w.y;
    acc[2] += a * w.z; acc[3] += a * w.w;
  }
  *(f32x4*)&part[rg][jq * 4] = acc;
  __syncthreads();
  {
    float v = (part[0][t] + part[1][t]) + (part[2][t] + part[3][t]) + bias[t];
    v *= scale;
    if (relu) v = fmaxf(v, 0.f);
    buf_out[t] = v;
  }
  __syncthreads();
}

__global__ __launch_bounds__(256) void mlp_kernel(
    const float* __restrict__ seg,
    const float* __restrict__ Wv1, const float* __restrict__ bv1,
    const float* __restrict__ Wv2, const float* __restrict__ bv2,
    const float* __restrict__ Wp1, const float* __restrict__ bp1,
    const float* __restrict__ Wp2, const float* __restrict__ bp2,
    float* __restrict__ out) {
  __shared__ __align__(16) float bufA[HDIM];
  __shared__ __align__(16) float bufB[HDIM];
  __shared__ __align__(16) float part[4][HDIM];   // aliased as [8][128] in L4
  const int t = threadIdx.x;
  const int g = blockIdx.x;

  bufA[t] = seg[g * HDIM + t] * 0.125f;
  __syncthreads();

  // relu(A@Wv1+b) -> B ; (B@Wv2+b) -> A ; relu(A@Wp1+b) -> B
  mlp_layer256(bufA, bufB, part, Wv1, bv1, true,  1.f, t);
  mlp_layer256(bufB, bufA, part, Wv2, bv2, false, 1.f, t);
  mlp_layer256(bufA, bufB, part, Wp1, bp1, true,  1.f, t);

  // layer 4: out[g] = B @ Wp2 + bp2, O=128. 8 k-chunks x 32 col-quads.
  {
    const int rg = t >> 5;        // [0,8)
    const int jq = t & 31;        // [0,32)
    f32x4 acc = {0.f, 0.f, 0.f, 0.f};
    const float4* wrow = (const float4*)(Wp2 + (size_t)rg * 32 * ODIM) + jq;
#pragma unroll 8
    for (int k = 0; k < 32; ++k) {
      float  a = bufB[rg * 32 + k];
      float4 w = wrow[(size_t)k * (ODIM / 4)];
      acc[0] += a * w.x; acc[1] += a * w.y;
      acc[2] += a * w.z; acc[3] += a * w.w;
    }
    float* p8 = &part[0][0];      // view as [8][128]
    *(f32x4*)&p8[rg * ODIM + jq * 4] = acc;
    __syncthreads();
    if (t < ODIM) {
      float v = bp2[t];
#pragma unroll
      for (int r = 0; r < 8; ++r) v += p8[r * ODIM + t];
      out[g * ODIM + t] = v;
    }
  }
}

// ---------------------------------------------------------------------------
extern "C" void kernel_launch(void* const* d_in, const int* in_sizes, int n_in,
                              void* d_out, int out_size, void* d_ws, size_t ws_size,
                              hipStream_t stream) {
  const float* x     = (const float*)d_in[0];
  // d_in[1] = edge_index : unused by the reference
  const int*   batch = (const int*)d_in[2];
  const float* W_enc = (const float*)d_in[3];
  const float* b_enc = (const float*)d_in[4];
  const float* W_v1  = (const float*)d_in[5];
  const float* b_v1  = (const float*)d_in[6];
  const float* W_v2  = (const float*)d_in[7];
  const float* b_v2  = (const float*)d_in[8];
  const float* W_p1  = (const float*)d_in[9];
  const float* b_p1  = (const float*)d_in[10];
  const float* W_p2  = (const float*)d_in[11];
  const float* b_p2  = (const float*)d_in[12];
  float* out = (float*)d_out;

  float*  seg = (float*)d_ws;                        // 256*256*4 = 262144 B
  __bf16* Bsw = (__bf16*)((char*)d_ws + 262144);     // 128*256*2 =  65536 B

  hipMemsetAsync(seg, 0, NGRAPH * HDIM * sizeof(float), stream);
  prep_kernel<<<16, 256, 0, stream>>>(W_enc, Bsw);
  enc_kernel<<<102400 / 64, 256, 0, stream>>>(x, batch, Bsw, b_enc, seg);
  mlp_kernel<<<NGRAPH, 256, 0, stream>>>(seg, W_v1, b_v1, W_v2, b_v2,
                                         W_p1, b_p1, W_p2, b_p2, out);
}